// Round 3
// 1016.418 us; speedup vs baseline: 1.1387x; 1.1387x over previous
//
#include <hip/hip_runtime.h>
#include <math.h>
#include <stdint.h>
#include <stddef.h>

#define BB 256
#define HHDIM 1024
#define DDIM 512
#define VDIM 50257
#define MMEM 100000

typedef __attribute__((ext_vector_type(8))) short bf8_t;       // 8 x bf16 (4 VGPR)
typedef __attribute__((ext_vector_type(4))) float f4_t;
typedef __attribute__((ext_vector_type(4))) unsigned short us4_t;

static __device__ __forceinline__ unsigned short f2bf(float x) {
    union { float f; uint32_t u; } a; a.f = x;
    uint32_t r = a.u + 0x7FFFu + ((a.u >> 16) & 1u);   // RNE
    return (unsigned short)(r >> 16);
}
static __device__ __forceinline__ float bf2f(unsigned short s) {
    union { uint32_t u; float f; } a; a.u = ((uint32_t)s) << 16; return a.f;
}

// ---------------------------------------------------------------------------
// Generic f32 tiled GEMM: C[B,N] = act(concat(A1,A2) @ [Wa;Wb]^T + bias)
// A1:[B,K1], A2:[B,K2], W rows are output features (row-major [N][K]).
// Optionally emits bf16 copy of first NSPLIT columns (for later MFMA use).
// ---------------------------------------------------------------------------
template<int BM, int BN>
__global__ __launch_bounds__(256) void gemm_f32_kernel(
    const float* __restrict__ A1, int K1, const float* __restrict__ A2, int K2,
    const float* __restrict__ Wa, const float* __restrict__ ba,
    const float* __restrict__ Wb, const float* __restrict__ bbias,
    int NSPLIT, int N, int RELU, float* __restrict__ C,
    unsigned short* __restrict__ ghout)
{
    const int K = K1 + K2;
    const int RM = BM / 16, RN = BN / 16;
    __shared__ float As[BM][33];
    __shared__ float Ws[BN][33];
    int t = threadIdx.x;
    int tx = t & 15, ty = t >> 4;
    int bb0 = blockIdx.x * BM;
    int nb0 = blockIdx.y * BN;
    float c[RM][RN];
#pragma unroll
    for (int i = 0; i < RM; ++i)
#pragma unroll
        for (int j = 0; j < RN; ++j) c[i][j] = 0.f;

    for (int k0 = 0; k0 < K; k0 += 32) {
        for (int idx = t; idx < BM * 8; idx += 256) {
            int row = idx >> 3, kq = idx & 7;
            int gk = k0 + kq * 4;
            float4 v;
            if (gk < K1) v = *(const float4*)(A1 + (size_t)(bb0 + row) * K1 + gk);
            else         v = *(const float4*)(A2 + (size_t)(bb0 + row) * K2 + (gk - K1));
            As[row][kq * 4 + 0] = v.x; As[row][kq * 4 + 1] = v.y;
            As[row][kq * 4 + 2] = v.z; As[row][kq * 4 + 3] = v.w;
        }
        for (int idx = t; idx < BN * 8; idx += 256) {
            int row = idx >> 3, kq = idx & 7;
            int gk = k0 + kq * 4;
            int n = nb0 + row;
            const float* wr = (n < NSPLIT) ? (Wa + (size_t)n * K)
                                           : (Wb + (size_t)(n - NSPLIT) * K);
            float4 v = *(const float4*)(wr + gk);
            Ws[row][kq * 4 + 0] = v.x; Ws[row][kq * 4 + 1] = v.y;
            Ws[row][kq * 4 + 2] = v.z; Ws[row][kq * 4 + 3] = v.w;
        }
        __syncthreads();
#pragma unroll
        for (int k = 0; k < 32; ++k) {
            float a[RM], w[RN];
#pragma unroll
            for (int i = 0; i < RM; ++i) a[i] = As[ty * RM + i][k];
#pragma unroll
            for (int j = 0; j < RN; ++j) w[j] = Ws[tx * RN + j][k];
#pragma unroll
            for (int i = 0; i < RM; ++i)
#pragma unroll
                for (int j = 0; j < RN; ++j) c[i][j] = fmaf(a[i], w[j], c[i][j]);
        }
        __syncthreads();
    }
#pragma unroll
    for (int i = 0; i < RM; ++i) {
#pragma unroll
        for (int j = 0; j < RN; ++j) {
            int b = bb0 + ty * RM + i;
            int n = nb0 + tx * RN + j;
            float bias = (n < NSPLIT) ? ba[n] : bbias[n - NSPLIT];
            float v = c[i][j] + bias;
            if (RELU) v = fmaxf(v, 0.f);
            C[(size_t)b * N + n] = v;
            if (ghout != nullptr && n < NSPLIT)
                ghout[(size_t)b * NSPLIT + n] = f2bf(v);
        }
    }
}

// ---------------------------------------------------------------------------
// qprep: per-row inverse norm of query + bf16 copy (plain row-major).
// ---------------------------------------------------------------------------
__global__ __launch_bounds__(256) void qprep_kernel(
    const float* __restrict__ query, float* __restrict__ qinv,
    unsigned short* __restrict__ gq)
{
    int b = blockIdx.x, t = threadIdx.x;
    int lane = t & 63, wid = t >> 6;
    __shared__ float red[4];
    float x0 = query[(size_t)b * 512 + t];
    float x1 = query[(size_t)b * 512 + 256 + t];
    float ss = x0 * x0 + x1 * x1;
#pragma unroll
    for (int off = 32; off; off >>= 1) ss += __shfl_down(ss, off);
    if (lane == 0) red[wid] = ss;
    __syncthreads();
    if (t == 0) qinv[b] = 1.0f / (sqrtf(red[0] + red[1] + red[2] + red[3]) + 1e-8f);
    gq[(size_t)b * 512 + t] = f2bf(x0);
    gq[(size_t)b * 512 + 256 + t] = f2bf(x1);
}

// ---------------------------------------------------------------------------
// sims: approx scores[b][m] = bf16( (q.k) * imp[m]/(|k|+eps) * 1/(|q|+eps) )
// MFMA M-dim = b (256, block-wide), N-dim = keys (128/block). K=512.
// ---------------------------------------------------------------------------
__global__ __launch_bounds__(256, 2) void sims_kernel(
    const float* __restrict__ keys, const float* __restrict__ imp,
    const unsigned short* __restrict__ gq, const float* __restrict__ qinv,
    unsigned short* __restrict__ scores)
{
    __shared__ unsigned short Aq[256 * 32];   // 16 KB, [b][32k] swizzled
    __shared__ unsigned short Bk[128 * 32];   // 8 KB,  [m][32k] swizzled
    __shared__ float sumsq_s[128];
    __shared__ float scale_s[128];
    __shared__ float qinv_s[256];
    int t = threadIdx.x, lane = t & 63, wid = t >> 6;
    int fr = lane & 15, fq = lane >> 4;
    int mbase = blockIdx.x * 128;
    int b0 = (wid >> 1) * 128;
    int m0 = (wid & 1) * 64;
    qinv_s[t] = qinv[t];
    if (t < 128) sumsq_s[t] = 0.f;

    f4_t acc[8][4];
#pragma unroll
    for (int i = 0; i < 8; ++i)
#pragma unroll
        for (int j = 0; j < 4; ++j) acc[i][j] = (f4_t){0.f, 0.f, 0.f, 0.f};
    float ps[4] = {0.f, 0.f, 0.f, 0.f};

    const int arow0 = t >> 2, ach = t & 3;
    const int bml0 = t >> 3, bkq = t & 7;

    for (int step = 0; step < 16; ++step) {
#pragma unroll
        for (int j = 0; j < 4; ++j) {
            int row = arow0 + 64 * j;
            bf8_t v = *(const bf8_t*)(const void*)(gq + (size_t)row * 512 + step * 32 + ach * 8);
            int slot = ach ^ ((row >> 1) & 3);
            *(bf8_t*)(void*)(&Aq[row * 32 + slot * 8]) = v;
        }
#pragma unroll
        for (int jj = 0; jj < 4; ++jj) {
            int ml = bml0 + 32 * jj;
            int gm = mbase + ml;
            float4 v = {0.f, 0.f, 0.f, 0.f};
            if (gm < MMEM) v = *(const float4*)(keys + (size_t)gm * 512 + step * 32 + bkq * 4);
            ps[jj] += v.x * v.x + v.y * v.y + v.z * v.z + v.w * v.w;
            us4_t pk; pk[0] = f2bf(v.x); pk[1] = f2bf(v.y); pk[2] = f2bf(v.z); pk[3] = f2bf(v.w);
            int slot = (bkq >> 1) ^ ((ml >> 1) & 3);
            *(us4_t*)(void*)(&Bk[ml * 32 + slot * 8 + (bkq & 1) * 4]) = pk;
        }
        __syncthreads();
        bf8_t af[8], bfr[4];
        int slotr = fq ^ ((fr >> 1) & 3);
#pragma unroll
        for (int i = 0; i < 8; ++i)
            af[i] = *(const bf8_t*)(const void*)(&Aq[(b0 + i * 16 + fr) * 32 + slotr * 8]);
#pragma unroll
        for (int j = 0; j < 4; ++j)
            bfr[j] = *(const bf8_t*)(const void*)(&Bk[(m0 + j * 16 + fr) * 32 + slotr * 8]);
#pragma unroll
        for (int i = 0; i < 8; ++i)
#pragma unroll
            for (int j = 0; j < 4; ++j)
                acc[i][j] = __builtin_amdgcn_mfma_f32_16x16x32_bf16(af[i], bfr[j], acc[i][j], 0, 0, 0);
        __syncthreads();
    }
#pragma unroll
    for (int jj = 0; jj < 4; ++jj) atomicAdd(&sumsq_s[bml0 + 32 * jj], ps[jj]);
    __syncthreads();
    if (t < 128) {
        int gm = mbase + t;
        float im = (gm < MMEM) ? imp[gm] : 0.f;
        scale_s[t] = im / (sqrtf(sumsq_s[t]) + 1e-8f);
    }
    __syncthreads();
#pragma unroll
    for (int i = 0; i < 8; ++i) {
        int brow = b0 + i * 16 + fq * 4;
#pragma unroll
        for (int j = 0; j < 4; ++j) {
            int mloc = m0 + j * 16 + fr;
            int gm = mbase + mloc;
            if (gm < MMEM) {
                float sc = scale_s[mloc];
#pragma unroll
                for (int r = 0; r < 4; ++r) {
                    float val = acc[i][j][r] * sc * qinv_s[brow + r];
                    scores[(size_t)(brow + r) * MMEM + gm] = f2bf(val);
                }
            }
        }
    }
}

// ---------------------------------------------------------------------------
// topk stage 1: chunked exact top-16. Grid = (25 chunks, 256 rows).
// Each thread holds 16 contiguous bf16 scores in REGISTERS (2x16B loads,
// statically indexed). Block extracts its chunk's top-16 via 16 rounds of
// shuffle+LDS argmax. Per-chunk top-16 union contains the global top-16.
// ---------------------------------------------------------------------------
#define TK_CHUNK 4096
#define TK_NCH   25     // ceil(MMEM / TK_CHUNK)

__global__ __launch_bounds__(256) void topk_stage1_kernel(
    const unsigned short* __restrict__ scores,
    float* __restrict__ cand_val, int* __restrict__ cand_idx)
{
    int chunk = blockIdx.x, b = blockIdx.y;
    int t = threadIdx.x, lane = t & 63, wid = t >> 6;
    __shared__ float wval[4]; __shared__ int wpay[4];
    __shared__ int winner_s;
    const unsigned short* srow = scores + (size_t)b * MMEM;
    int base = chunk * TK_CHUNK;
    int m0 = base + t * 16;
    float v[16];
    if (m0 + 16 <= MMEM) {
        bf8_t s0 = *(const bf8_t*)(const void*)(srow + m0);
        bf8_t s1 = *(const bf8_t*)(const void*)(srow + m0 + 8);
#pragma unroll
        for (int j = 0; j < 8; ++j) v[j] = bf2f((unsigned short)s0[j]);
#pragma unroll
        for (int j = 0; j < 8; ++j) v[8 + j] = bf2f((unsigned short)s1[j]);
    } else {
#pragma unroll
        for (int j = 0; j < 16; ++j)
            v[j] = (m0 + j < MMEM) ? bf2f(srow[m0 + j]) : -1e30f;
    }
    // per-thread running argmax over the 16 register values
    float bm = v[0]; int bp = 0;
#pragma unroll
    for (int p = 1; p < 16; ++p) if (v[p] > bm) { bm = v[p]; bp = p; }

    for (int r = 0; r < 16; ++r) {
        float mv = bm; int mp = (t << 4) | bp;
#pragma unroll
        for (int off = 32; off; off >>= 1) {
            float ov = __shfl_down(mv, off); int op = __shfl_down(mp, off);
            if (ov > mv) { mv = ov; mp = op; }
        }
        if (lane == 0) { wval[wid] = mv; wpay[wid] = mp; }
        __syncthreads();
        if (t == 0) {
            float bv = wval[0]; int bpay = wpay[0];
#pragma unroll
            for (int w = 1; w < 4; ++w) if (wval[w] > bv) { bv = wval[w]; bpay = wpay[w]; }
            int o = ((b * TK_NCH + chunk) << 4) | r;
            cand_val[o] = bv;
            cand_idx[o] = base + (bpay >> 4) * 16 + (bpay & 15);
            winner_s = bpay;
        }
        __syncthreads();
        if (t == (winner_s >> 4)) {
            int slot = winner_s & 15;
#pragma unroll
            for (int p = 0; p < 16; ++p) if (p == slot) v[p] = -1e30f;
            bm = v[0]; bp = 0;
#pragma unroll
            for (int p = 1; p < 16; ++p) if (v[p] > bm) { bm = v[p]; bp = p; }
        }
        // winner_s is rewritten only after the next round's first barrier,
        // which all threads reach after the read above -> no race.
    }
}

// ---------------------------------------------------------------------------
// topk stage 2: per row merge 25*16=400 candidates -> global top-16 ->
// exact f32 rescore -> top-8 -> softmax -> context. One block per row.
// ---------------------------------------------------------------------------
__global__ __launch_bounds__(256) void topk_refine2_kernel(
    const float* __restrict__ cand_val, const int* __restrict__ cand_idx,
    const float* __restrict__ keys, const float* __restrict__ values,
    const float* __restrict__ imp, const float* __restrict__ query,
    const float* __restrict__ qinv, float* __restrict__ context)
{
    int b = blockIdx.x, t = threadIdx.x;
    int lane = t & 63, wid = t >> 6;
    __shared__ float q_s[512];
    __shared__ float wval[4]; __shared__ int wpay[4];
    __shared__ int winner_s;
    __shared__ int cidx[16]; __shared__ float csc[16];
    __shared__ float attn_s[8]; __shared__ int vidx_s[8];

    q_s[t] = query[(size_t)b * 512 + t];
    q_s[t + 256] = query[(size_t)b * 512 + 256 + t];

    const float* cvb = cand_val + b * (TK_NCH * 16);
    const int*   cib = cand_idx + b * (TK_NCH * 16);
    float v0 = cvb[t]; int i0 = cib[t];
    float v1 = -1e30f;  int i1 = 0;
    if (t < TK_NCH * 16 - 256) { v1 = cvb[t + 256]; i1 = cib[t + 256]; }
    float bm; int bp;
    if (v1 > v0) { bm = v1; bp = 1; } else { bm = v0; bp = 0; }

    for (int r = 0; r < 16; ++r) {
        float mv = bm; int mp = (t << 1) | bp;
#pragma unroll
        for (int off = 32; off; off >>= 1) {
            float ov = __shfl_down(mv, off); int op = __shfl_down(mp, off);
            if (ov > mv) { mv = ov; mp = op; }
        }
        if (lane == 0) { wval[wid] = mv; wpay[wid] = mp; }
        __syncthreads();
        if (t == 0) {
            float bv = wval[0]; int bpay = wpay[0];
#pragma unroll
            for (int w = 1; w < 4; ++w) if (wval[w] > bv) { bv = wval[w]; bpay = wpay[w]; }
            winner_s = bpay;
        }
        __syncthreads();
        if (t == (winner_s >> 1)) {
            int slot = winner_s & 1;
            cidx[r] = slot ? i1 : i0;
            if (slot == 0) v0 = -1e30f; else v1 = -1e30f;
            if (v1 > v0) { bm = v1; bp = 1; } else { bm = v0; bp = 0; }
        }
    }
    __syncthreads();
    // exact f32 rescore: wave wid handles candidates wid*4 .. wid*4+3
    for (int cc = 0; cc < 4; ++cc) {
        int c = wid * 4 + cc;
        int mi = cidx[c];
        const float* krow = keys + (size_t)mi * 512;
        float4 k1 = *(const float4*)(krow + lane * 8);
        float4 k2 = *(const float4*)(krow + lane * 8 + 4);
        int q0 = lane * 8;
        float dot = k1.x * q_s[q0] + k1.y * q_s[q0 + 1] + k1.z * q_s[q0 + 2] + k1.w * q_s[q0 + 3]
                  + k2.x * q_s[q0 + 4] + k2.y * q_s[q0 + 5] + k2.z * q_s[q0 + 6] + k2.w * q_s[q0 + 7];
        float nr = k1.x * k1.x + k1.y * k1.y + k1.z * k1.z + k1.w * k1.w
                 + k2.x * k2.x + k2.y * k2.y + k2.z * k2.z + k2.w * k2.w;
#pragma unroll
        for (int off = 32; off; off >>= 1) {
            dot += __shfl_down(dot, off);
            nr  += __shfl_down(nr, off);
        }
        if (lane == 0)
            csc[c] = dot * qinv[b] * imp[mi] / (sqrtf(nr) + 1e-8f);
    }
    __syncthreads();
    if (t == 0) {
        unsigned used = 0;
        float sv[8]; int si[8];
#pragma unroll
        for (int r = 0; r < 8; ++r) {
            float bmx = -1e31f; int bpp = 0;
            for (int p = 0; p < 16; ++p)
                if (!((used >> p) & 1u) && csc[p] > bmx) { bmx = csc[p]; bpp = p; }
            used |= 1u << bpp; sv[r] = bmx; si[r] = cidx[bpp];
        }
        float mx = sv[0];
        float ee[8]; float den = 0.f;
#pragma unroll
        for (int r = 0; r < 8; ++r) { ee[r] = expf(sv[r] - mx); den += ee[r]; }
#pragma unroll
        for (int r = 0; r < 8; ++r) { attn_s[r] = ee[r] / den; vidx_s[r] = si[r]; }
    }
    __syncthreads();
    int d0 = t * 2;
    float c0 = 0.f, c1 = 0.f;
#pragma unroll
    for (int r = 0; r < 8; ++r) {
        float w = attn_s[r];
        const float* vrow = values + (size_t)vidx_s[r] * 512;
        float2 vv = *(const float2*)(vrow + d0);
        c0 += w * vv.x; c1 += w * vv.y;
    }
    float2 outv; outv.x = c0; outv.y = c1;
    *(float2*)(context + (size_t)b * 512 + d0) = outv;
}

// ---------------------------------------------------------------------------
// logits: out[b][v] = (h_p @ Wp2^T)[b][v] + bp2[v].
// ---------------------------------------------------------------------------
__global__ __launch_bounds__(256, 2) void logits_kernel(
    const float* __restrict__ Wp2, const float* __restrict__ bp2,
    const unsigned short* __restrict__ gh, float* __restrict__ out)
{
    __shared__ unsigned short Ah[256 * 32];
    __shared__ unsigned short Bw[128 * 32];
    __shared__ float bias_s[128];
    int t = threadIdx.x, lane = t & 63, wid = t >> 6;
    int fr = lane & 15, fq = lane >> 4;
    int vbase = blockIdx.x * 128;
    int b0 = (wid >> 1) * 128;
    int m0 = (wid & 1) * 64;
    if (t < 128) { int gv = vbase + t; bias_s[t] = (gv < VDIM) ? bp2[gv] : 0.f; }

    f4_t acc[8][4];
#pragma unroll
    for (int i = 0; i < 8; ++i)
#pragma unroll
        for (int j = 0; j < 4; ++j) acc[i][j] = (f4_t){0.f, 0.f, 0.f, 0.f};

    const int arow0 = t >> 2, ach = t & 3;
    const int bml0 = t >> 3, bkq = t & 7;

    for (int step = 0; step < 32; ++step) {
#pragma unroll
        for (int j = 0; j < 4; ++j) {
            int row = arow0 + 64 * j;
            bf8_t v = *(const bf8_t*)(const void*)(gh + (size_t)row * 1024 + step * 32 + ach * 8);
            int slot = ach ^ ((row >> 1) & 3);
            *(bf8_t*)(void*)(&Ah[row * 32 + slot * 8]) = v;
        }
#pragma unroll
        for (int jj = 0; jj < 4; ++jj) {
            int ml = bml0 + 32 * jj;
            int gv = vbase + ml;
            float4 v = {0.f, 0.f, 0.f, 0.f};
            if (gv < VDIM) v = *(const float4*)(Wp2 + (size_t)gv * 1024 + step * 32 + bkq * 4);
            us4_t pk; pk[0] = f2bf(v.x); pk[1] = f2bf(v.y); pk[2] = f2bf(v.z); pk[3] = f2bf(v.w);
            int slot = (bkq >> 1) ^ ((ml >> 1) & 3);
            *(us4_t*)(void*)(&Bw[ml * 32 + slot * 8 + (bkq & 1) * 4]) = pk;
        }
        __syncthreads();
        bf8_t af[8], bfr[4];
        int slotr = fq ^ ((fr >> 1) & 3);
#pragma unroll
        for (int i = 0; i < 8; ++i)
            af[i] = *(const bf8_t*)(const void*)(&Ah[(b0 + i * 16 + fr) * 32 + slotr * 8]);
#pragma unroll
        for (int j = 0; j < 4; ++j)
            bfr[j] = *(const bf8_t*)(const void*)(&Bw[(m0 + j * 16 + fr) * 32 + slotr * 8]);
#pragma unroll
        for (int i = 0; i < 8; ++i)
#pragma unroll
            for (int j = 0; j < 4; ++j)
                acc[i][j] = __builtin_amdgcn_mfma_f32_16x16x32_bf16(af[i], bfr[j], acc[i][j], 0, 0, 0);
        __syncthreads();
    }
#pragma unroll
    for (int i = 0; i < 8; ++i) {
        int brow = b0 + i * 16 + fq * 4;
#pragma unroll
        for (int j = 0; j < 4; ++j) {
            int vloc = m0 + j * 16 + fr;
            int gv = vbase + vloc;
            if (gv < VDIM) {
                float bias = bias_s[vloc];
#pragma unroll
                for (int r = 0; r < 4; ++r)
                    out[(size_t)(brow + r) * VDIM + gv] = acc[i][j][r] + bias;
            }
        }
    }
}

// ---------------------------------------------------------------------------
// value head: out[B*V + b] = h_v[b,:] . Wv2 + bv2.  One wave per batch row.
// ---------------------------------------------------------------------------
__global__ __launch_bounds__(256) void value_kernel(
    const float* __restrict__ hcomb, const float* __restrict__ Wv2,
    const float* __restrict__ bv2, float* __restrict__ out)
{
    int lane = threadIdx.x & 63, wid = threadIdx.x >> 6;
    int b = blockIdx.x * 4 + wid;
    float s = 0.f;
#pragma unroll
    for (int i = 0; i < 16; ++i) {
        int k = lane + 64 * i;
        s += hcomb[(size_t)b * 2048 + 1024 + k] * Wv2[k];
    }
#pragma unroll
    for (int off = 32; off; off >>= 1) s += __shfl_down(s, off);
    if (lane == 0) out[(size_t)BB * VDIM + b] = s + bv2[0];
}

// ---------------------------------------------------------------------------
extern "C" void kernel_launch(void* const* d_in, const int* in_sizes, int n_in,
                              void* d_out, int out_size, void* d_ws, size_t ws_size,
                              hipStream_t stream)
{
    const float* hidden = (const float*)d_in[0];
    const float* keys   = (const float*)d_in[1];
    const float* values = (const float*)d_in[2];
    const float* imp    = (const float*)d_in[3];
    const float* Wq  = (const float*)d_in[4];
    const float* bq  = (const float*)d_in[5];
    const float* Wp1 = (const float*)d_in[6];
    const float* bp1 = (const float*)d_in[7];
    const float* Wp2 = (const float*)d_in[8];
    const float* bp2 = (const float*)d_in[9];
    const float* Wv1 = (const float*)d_in[10];
    const float* bv1 = (const float*)d_in[11];
    const float* Wv2 = (const float*)d_in[12];
    const float* bv2 = (const float*)d_in[13];
    // d_in[14] = top_k (always 8 in this problem's setup)
    float* out = (float*)d_out;
    char* ws = (char*)d_ws;

    float*          query   = (float*)(ws + 0);                      // 524288 B
    float*          qinv    = (float*)(ws + 524288);                 //   1024 B
    unsigned short* gq      = (unsigned short*)(ws + 525312);        // 262144 B
    float*          context = (float*)(ws + 787456);                 // 524288 B
    float*          hcomb   = (float*)(ws + 1311744);                // 2097152 B
    unsigned short* gh      = (unsigned short*)(ws + 3408896);       // 524288 B
    unsigned short* scores  = (unsigned short*)(ws + 3933184);       // 51200000 B
    // candidate buffers OVERLAY the hcomb region: they are produced by
    // topk_stage1 and fully consumed by topk_refine2 BEFORE step 5 writes
    // hcomb (same stream => serialized; graph capture preserves order).
    float* cand_val = (float*)(ws + 1311744);                        // 409600 B
    int*   cand_idx = (int*)  (ws + 1311744 + 409600);               // 409600 B

    // 1. query = hidden @ Wq^T + bq   (exact f32 — selection depends on it)
    gemm_f32_kernel<16, 64><<<dim3(16, 8), 256, 0, stream>>>(
        hidden, 1024, nullptr, 0, Wq, bq, nullptr, nullptr, 512, 512, 0, query, nullptr);
    // 2. query norms + bf16 copy
    qprep_kernel<<<256, 256, 0, stream>>>(query, qinv, gq);
    // 3. approx sims (bf16 MFMA) -> bf16 score matrix
    sims_kernel<<<782, 256, 0, stream>>>(keys, imp, gq, qinv, scores);
    // 4a. chunked exact top-16 per (row, chunk): registers only, 25 blocks/row
    topk_stage1_kernel<<<dim3(TK_NCH, 256), 256, 0, stream>>>(scores, cand_val, cand_idx);
    // 4b. merge 400 candidates -> top-16 -> exact rescore -> top-8 -> context
    topk_refine2_kernel<<<256, 256, 0, stream>>>(
        cand_val, cand_idx, keys, values, imp, query, qinv, context);
    // 5. h_p / h_v = relu([hidden|context] @ [Wp1;Wv1]^T + b)  (f32, emits bf16 h_p)
    gemm_f32_kernel<32, 64><<<dim3(8, 32), 256, 0, stream>>>(
        hidden, 1024, context, 512, Wp1, bp1, Wv1, bv1, 1024, 2048, 1, hcomb, gh);
    // 6. logits = h_p @ Wp2^T + bp2  (bf16 MFMA, f32 out)
    logits_kernel<<<393, 256, 0, stream>>>(Wp2, bp2, gh, out);
    // 7. value head
    value_kernel<<<64, 256, 0, stream>>>(hcomb, Wv2, bv2, out);
}

// Round 4
// 909.967 us; speedup vs baseline: 1.2719x; 1.1170x over previous
//
#include <hip/hip_runtime.h>
#include <math.h>
#include <stdint.h>
#include <stddef.h>

#define BB 256
#define HHDIM 1024
#define DDIM 512
#define VDIM 50257
#define MMEM 100000

typedef __attribute__((ext_vector_type(8))) short bf8_t;       // 8 x bf16 (4 VGPR)
typedef __attribute__((ext_vector_type(4))) float f4_t;
typedef __attribute__((ext_vector_type(4))) unsigned short us4_t;

static __device__ __forceinline__ unsigned short f2bf(float x) {
    union { float f; uint32_t u; } a; a.f = x;
    uint32_t r = a.u + 0x7FFFu + ((a.u >> 16) & 1u);   // RNE
    return (unsigned short)(r >> 16);
}
static __device__ __forceinline__ float bf2f(unsigned short s) {
    union { uint32_t u; float f; } a; a.u = ((uint32_t)s) << 16; return a.f;
}

// async global->LDS, 16B per lane. LDS dest must be linear in lane order.
static __device__ __forceinline__ void glds16(const unsigned short* g, unsigned short* l) {
    __builtin_amdgcn_global_load_lds(
        (const __attribute__((address_space(1))) unsigned int*)g,
        (__attribute__((address_space(3))) unsigned int*)l, 16, 0, 0);
}

// ---------------------------------------------------------------------------
// Generic f32 tiled GEMM: C[B,N] = act(concat(A1,A2) @ [Wa;Wb]^T + bias)
// ---------------------------------------------------------------------------
template<int BM, int BN>
__global__ __launch_bounds__(256) void gemm_f32_kernel(
    const float* __restrict__ A1, int K1, const float* __restrict__ A2, int K2,
    const float* __restrict__ Wa, const float* __restrict__ ba,
    const float* __restrict__ Wb, const float* __restrict__ bbias,
    int NSPLIT, int N, int RELU, float* __restrict__ C,
    unsigned short* __restrict__ ghout)
{
    const int K = K1 + K2;
    const int RM = BM / 16, RN = BN / 16;
    __shared__ float As[BM][33];
    __shared__ float Ws[BN][33];
    int t = threadIdx.x;
    int tx = t & 15, ty = t >> 4;
    int bb0 = blockIdx.x * BM;
    int nb0 = blockIdx.y * BN;
    float c[RM][RN];
#pragma unroll
    for (int i = 0; i < RM; ++i)
#pragma unroll
        for (int j = 0; j < RN; ++j) c[i][j] = 0.f;

    for (int k0 = 0; k0 < K; k0 += 32) {
        for (int idx = t; idx < BM * 8; idx += 256) {
            int row = idx >> 3, kq = idx & 7;
            int gk = k0 + kq * 4;
            float4 v;
            if (gk < K1) v = *(const float4*)(A1 + (size_t)(bb0 + row) * K1 + gk);
            else         v = *(const float4*)(A2 + (size_t)(bb0 + row) * K2 + (gk - K1));
            As[row][kq * 4 + 0] = v.x; As[row][kq * 4 + 1] = v.y;
            As[row][kq * 4 + 2] = v.z; As[row][kq * 4 + 3] = v.w;
        }
        for (int idx = t; idx < BN * 8; idx += 256) {
            int row = idx >> 3, kq = idx & 7;
            int gk = k0 + kq * 4;
            int n = nb0 + row;
            const float* wr = (n < NSPLIT) ? (Wa + (size_t)n * K)
                                           : (Wb + (size_t)(n - NSPLIT) * K);
            float4 v = *(const float4*)(wr + gk);
            Ws[row][kq * 4 + 0] = v.x; Ws[row][kq * 4 + 1] = v.y;
            Ws[row][kq * 4 + 2] = v.z; Ws[row][kq * 4 + 3] = v.w;
        }
        __syncthreads();
#pragma unroll
        for (int k = 0; k < 32; ++k) {
            float a[RM], w[RN];
#pragma unroll
            for (int i = 0; i < RM; ++i) a[i] = As[ty * RM + i][k];
#pragma unroll
            for (int j = 0; j < RN; ++j) w[j] = Ws[tx * RN + j][k];
#pragma unroll
            for (int i = 0; i < RM; ++i)
#pragma unroll
                for (int j = 0; j < RN; ++j) c[i][j] = fmaf(a[i], w[j], c[i][j]);
        }
        __syncthreads();
    }
#pragma unroll
    for (int i = 0; i < RM; ++i) {
#pragma unroll
        for (int j = 0; j < RN; ++j) {
            int b = bb0 + ty * RM + i;
            int n = nb0 + tx * RN + j;
            float bias = (n < NSPLIT) ? ba[n] : bbias[n - NSPLIT];
            float v = c[i][j] + bias;
            if (RELU) v = fmaxf(v, 0.f);
            C[(size_t)b * N + n] = v;
            if (ghout != nullptr && n < NSPLIT)
                ghout[(size_t)b * NSPLIT + n] = f2bf(v);
        }
    }
}

// ---------------------------------------------------------------------------
// qprep: per-row inverse norm of query + bf16 copy (plain row-major).
// ---------------------------------------------------------------------------
__global__ __launch_bounds__(256) void qprep_kernel(
    const float* __restrict__ query, float* __restrict__ qinv,
    unsigned short* __restrict__ gq)
{
    int b = blockIdx.x, t = threadIdx.x;
    int lane = t & 63, wid = t >> 6;
    __shared__ float red[4];
    float x0 = query[(size_t)b * 512 + t];
    float x1 = query[(size_t)b * 512 + 256 + t];
    float ss = x0 * x0 + x1 * x1;
#pragma unroll
    for (int off = 32; off; off >>= 1) ss += __shfl_down(ss, off);
    if (lane == 0) red[wid] = ss;
    __syncthreads();
    if (t == 0) qinv[b] = 1.0f / (sqrtf(red[0] + red[1] + red[2] + red[3]) + 1e-8f);
    gq[(size_t)b * 512 + t] = f2bf(x0);
    gq[(size_t)b * 512 + 256 + t] = f2bf(x1);
}

// ---------------------------------------------------------------------------
// sims v2: pipelined. Double-buffered LDS, ONE barrier per K-step.
// A (gq bf16) staged via global_load_lds with source-side XOR swizzle.
// B (keys f32) loads issued at step top into regs; sumsq+f2bf+ds_write after
// the MFMA phase -> HBM latency hides under dsread+MFMA.
// ---------------------------------------------------------------------------
__global__ __launch_bounds__(256, 2) void sims_kernel(
    const float* __restrict__ keys, const float* __restrict__ imp,
    const unsigned short* __restrict__ gq, const float* __restrict__ qinv,
    unsigned short* __restrict__ scores)
{
    __shared__ unsigned short Aq[2][256 * 32];   // 2 x 16 KB
    __shared__ unsigned short Bk[2][128 * 32];   // 2 x 8 KB
    __shared__ float sumsq_s[128];
    __shared__ float scale_s[128];
    __shared__ float qinv_s[256];
    int t = threadIdx.x, lane = t & 63, wid = t >> 6;
    int fr = lane & 15, fq = lane >> 4;
    int mbase = blockIdx.x * 128;
    int b0 = (wid >> 1) * 128;
    int m0 = (wid & 1) * 64;
    qinv_s[t] = qinv[t];
    if (t < 128) sumsq_s[t] = 0.f;

    f4_t acc[8][4];
#pragma unroll
    for (int i = 0; i < 8; ++i)
#pragma unroll
        for (int j = 0; j < 4; ++j) acc[i][j] = (f4_t){0.f, 0.f, 0.f, 0.f};
    float ps[4] = {0.f, 0.f, 0.f, 0.f};

    const int bml0 = t >> 3, bkq = t & 7;
    // per-jj row validity + base pointer (uniform over steps)
    int   gmr[4];  bool gmv[4];
#pragma unroll
    for (int jj = 0; jj < 4; ++jj) {
        gmr[jj] = mbase + bml0 + 32 * jj;
        gmv[jj] = gmr[jj] < MMEM;
    }

    // ---- prologue: stage step 0 into buffer 0 ----
#pragma unroll
    for (int j = 0; j < 4; ++j) {
        int c = t + 256 * j;
        int row = c >> 2, slot = c & 3;
        int ach = slot ^ ((row >> 1) & 3);
        glds16(gq + (size_t)row * 512 + ach * 8, &Aq[0][c * 8]);
    }
    float4 kreg[4];
#pragma unroll
    for (int jj = 0; jj < 4; ++jj)
        kreg[jj] = gmv[jj] ? *(const float4*)(keys + (size_t)gmr[jj] * 512 + bkq * 4)
                           : (float4){0.f, 0.f, 0.f, 0.f};
#pragma unroll
    for (int jj = 0; jj < 4; ++jj) {
        int ml = bml0 + 32 * jj;
        float4 v = kreg[jj];
        ps[jj] += v.x * v.x + v.y * v.y + v.z * v.z + v.w * v.w;
        us4_t pk; pk[0] = f2bf(v.x); pk[1] = f2bf(v.y); pk[2] = f2bf(v.z); pk[3] = f2bf(v.w);
        int slot = (bkq >> 1) ^ ((ml >> 1) & 3);
        *(us4_t*)(void*)(&Bk[0][ml * 32 + slot * 8 + (bkq & 1) * 4]) = pk;
    }
    __syncthreads();

    for (int s = 0; s < 16; ++s) {
        int cur = s & 1, nxt = cur ^ 1;
        if (s < 15) {
            // B loads for s+1 first (vmcnt wait before their use won't
            // cover the glds issued after them)
#pragma unroll
            for (int jj = 0; jj < 4; ++jj)
                kreg[jj] = gmv[jj]
                    ? *(const float4*)(keys + (size_t)gmr[jj] * 512 + (s + 1) * 32 + bkq * 4)
                    : (float4){0.f, 0.f, 0.f, 0.f};
            // A(s+1) async into other buffer
#pragma unroll
            for (int j = 0; j < 4; ++j) {
                int c = t + 256 * j;
                int row = c >> 2, slot = c & 3;
                int ach = slot ^ ((row >> 1) & 3);
                glds16(gq + (size_t)row * 512 + (s + 1) * 32 + ach * 8, &Aq[nxt][c * 8]);
            }
        }
        // compute on current buffers
        bf8_t af[8], bfr[4];
        int slotr = fq ^ ((fr >> 1) & 3);
#pragma unroll
        for (int i = 0; i < 8; ++i)
            af[i] = *(const bf8_t*)(const void*)(&Aq[cur][(b0 + i * 16 + fr) * 32 + slotr * 8]);
#pragma unroll
        for (int j = 0; j < 4; ++j)
            bfr[j] = *(const bf8_t*)(const void*)(&Bk[cur][(m0 + j * 16 + fr) * 32 + slotr * 8]);
#pragma unroll
        for (int i = 0; i < 8; ++i)
#pragma unroll
            for (int j = 0; j < 4; ++j)
                acc[i][j] = __builtin_amdgcn_mfma_f32_16x16x32_bf16(af[i], bfr[j], acc[i][j], 0, 0, 0);
        if (s < 15) {
            // consume prefetched B: sumsq + convert + write to next buffer
#pragma unroll
            for (int jj = 0; jj < 4; ++jj) {
                int ml = bml0 + 32 * jj;
                float4 v = kreg[jj];
                ps[jj] += v.x * v.x + v.y * v.y + v.z * v.z + v.w * v.w;
                us4_t pk; pk[0] = f2bf(v.x); pk[1] = f2bf(v.y); pk[2] = f2bf(v.z); pk[3] = f2bf(v.w);
                int slot = (bkq >> 1) ^ ((ml >> 1) & 3);
                *(us4_t*)(void*)(&Bk[nxt][ml * 32 + slot * 8 + (bkq & 1) * 4]) = pk;
            }
        }
        __syncthreads();
    }
#pragma unroll
    for (int jj = 0; jj < 4; ++jj) atomicAdd(&sumsq_s[bml0 + 32 * jj], ps[jj]);
    __syncthreads();
    if (t < 128) {
        int gm = mbase + t;
        float im = (gm < MMEM) ? imp[gm] : 0.f;
        scale_s[t] = im / (sqrtf(sumsq_s[t]) + 1e-8f);
    }
    __syncthreads();
#pragma unroll
    for (int i = 0; i < 8; ++i) {
        int brow = b0 + i * 16 + fq * 4;
#pragma unroll
        for (int j = 0; j < 4; ++j) {
            int mloc = m0 + j * 16 + fr;
            int gm = mbase + mloc;
            if (gm < MMEM) {
                float sc = scale_s[mloc];
#pragma unroll
                for (int r = 0; r < 4; ++r) {
                    float val = acc[i][j][r] * sc * qinv_s[brow + r];
                    scores[(size_t)(brow + r) * MMEM + gm] = f2bf(val);
                }
            }
        }
    }
}

// ---------------------------------------------------------------------------
// topk stage 1: chunked exact top-16. Grid = (25 chunks, 256 rows).
// ---------------------------------------------------------------------------
#define TK_CHUNK 4096
#define TK_NCH   25     // ceil(MMEM / TK_CHUNK)

__global__ __launch_bounds__(256) void topk_stage1_kernel(
    const unsigned short* __restrict__ scores,
    float* __restrict__ cand_val, int* __restrict__ cand_idx)
{
    int chunk = blockIdx.x, b = blockIdx.y;
    int t = threadIdx.x, lane = t & 63, wid = t >> 6;
    __shared__ float wval[4]; __shared__ int wpay[4];
    __shared__ int winner_s;
    const unsigned short* srow = scores + (size_t)b * MMEM;
    int base = chunk * TK_CHUNK;
    int m0 = base + t * 16;
    float v[16];
    if (m0 + 16 <= MMEM) {
        bf8_t s0 = *(const bf8_t*)(const void*)(srow + m0);
        bf8_t s1 = *(const bf8_t*)(const void*)(srow + m0 + 8);
#pragma unroll
        for (int j = 0; j < 8; ++j) v[j] = bf2f((unsigned short)s0[j]);
#pragma unroll
        for (int j = 0; j < 8; ++j) v[8 + j] = bf2f((unsigned short)s1[j]);
    } else {
#pragma unroll
        for (int j = 0; j < 16; ++j)
            v[j] = (m0 + j < MMEM) ? bf2f(srow[m0 + j]) : -1e30f;
    }
    float bm = v[0]; int bp = 0;
#pragma unroll
    for (int p = 1; p < 16; ++p) if (v[p] > bm) { bm = v[p]; bp = p; }

    for (int r = 0; r < 16; ++r) {
        float mv = bm; int mp = (t << 4) | bp;
#pragma unroll
        for (int off = 32; off; off >>= 1) {
            float ov = __shfl_down(mv, off); int op = __shfl_down(mp, off);
            if (ov > mv) { mv = ov; mp = op; }
        }
        if (lane == 0) { wval[wid] = mv; wpay[wid] = mp; }
        __syncthreads();
        if (t == 0) {
            float bv = wval[0]; int bpay = wpay[0];
#pragma unroll
            for (int w = 1; w < 4; ++w) if (wval[w] > bv) { bv = wval[w]; bpay = wpay[w]; }
            int o = ((b * TK_NCH + chunk) << 4) | r;
            cand_val[o] = bv;
            cand_idx[o] = base + (bpay >> 4) * 16 + (bpay & 15);
            winner_s = bpay;
        }
        __syncthreads();
        if (t == (winner_s >> 4)) {
            int slot = winner_s & 15;
#pragma unroll
            for (int p = 0; p < 16; ++p) if (p == slot) v[p] = -1e30f;
            bm = v[0]; bp = 0;
#pragma unroll
            for (int p = 1; p < 16; ++p) if (v[p] > bm) { bm = v[p]; bp = p; }
        }
    }
}

// ---------------------------------------------------------------------------
// topk stage 2: merge 400 candidates -> top-16 -> exact rescore -> top-8
// -> softmax -> context. One block per row.
// ---------------------------------------------------------------------------
__global__ __launch_bounds__(256) void topk_refine2_kernel(
    const float* __restrict__ cand_val, const int* __restrict__ cand_idx,
    const float* __restrict__ keys, const float* __restrict__ values,
    const float* __restrict__ imp, const float* __restrict__ query,
    const float* __restrict__ qinv, float* __restrict__ context)
{
    int b = blockIdx.x, t = threadIdx.x;
    int lane = t & 63, wid = t >> 6;
    __shared__ float q_s[512];
    __shared__ float wval[4]; __shared__ int wpay[4];
    __shared__ int winner_s;
    __shared__ int cidx[16]; __shared__ float csc[16];
    __shared__ float attn_s[8]; __shared__ int vidx_s[8];

    q_s[t] = query[(size_t)b * 512 + t];
    q_s[t + 256] = query[(size_t)b * 512 + 256 + t];

    const float* cvb = cand_val + b * (TK_NCH * 16);
    const int*   cib = cand_idx + b * (TK_NCH * 16);
    float v0 = cvb[t]; int i0 = cib[t];
    float v1 = -1e30f;  int i1 = 0;
    if (t < TK_NCH * 16 - 256) { v1 = cvb[t + 256]; i1 = cib[t + 256]; }
    float bm; int bp;
    if (v1 > v0) { bm = v1; bp = 1; } else { bm = v0; bp = 0; }

    for (int r = 0; r < 16; ++r) {
        float mv = bm; int mp = (t << 1) | bp;
#pragma unroll
        for (int off = 32; off; off >>= 1) {
            float ov = __shfl_down(mv, off); int op = __shfl_down(mp, off);
            if (ov > mv) { mv = ov; mp = op; }
        }
        if (lane == 0) { wval[wid] = mv; wpay[wid] = mp; }
        __syncthreads();
        if (t == 0) {
            float bv = wval[0]; int bpay = wpay[0];
#pragma unroll
            for (int w = 1; w < 4; ++w) if (wval[w] > bv) { bv = wval[w]; bpay = wpay[w]; }
            winner_s = bpay;
        }
        __syncthreads();
        if (t == (winner_s >> 1)) {
            int slot = winner_s & 1;
            cidx[r] = slot ? i1 : i0;
            if (slot == 0) v0 = -1e30f; else v1 = -1e30f;
            if (v1 > v0) { bm = v1; bp = 1; } else { bm = v0; bp = 0; }
        }
    }
    __syncthreads();
    for (int cc = 0; cc < 4; ++cc) {
        int c = wid * 4 + cc;
        int mi = cidx[c];
        const float* krow = keys + (size_t)mi * 512;
        float4 k1 = *(const float4*)(krow + lane * 8);
        float4 k2 = *(const float4*)(krow + lane * 8 + 4);
        int q0 = lane * 8;
        float dot = k1.x * q_s[q0] + k1.y * q_s[q0 + 1] + k1.z * q_s[q0 + 2] + k1.w * q_s[q0 + 3]
                  + k2.x * q_s[q0 + 4] + k2.y * q_s[q0 + 5] + k2.z * q_s[q0 + 6] + k2.w * q_s[q0 + 7];
        float nr = k1.x * k1.x + k1.y * k1.y + k1.z * k1.z + k1.w * k1.w
                 + k2.x * k2.x + k2.y * k2.y + k2.z * k2.z + k2.w * k2.w;
#pragma unroll
        for (int off = 32; off; off >>= 1) {
            dot += __shfl_down(dot, off);
            nr  += __shfl_down(nr, off);
        }
        if (lane == 0)
            csc[c] = dot * qinv[b] * imp[mi] / (sqrtf(nr) + 1e-8f);
    }
    __syncthreads();
    if (t == 0) {
        unsigned used = 0;
        float sv[8]; int si[8];
#pragma unroll
        for (int r = 0; r < 8; ++r) {
            float bmx = -1e31f; int bpp = 0;
            for (int p = 0; p < 16; ++p)
                if (!((used >> p) & 1u) && csc[p] > bmx) { bmx = csc[p]; bpp = p; }
            used |= 1u << bpp; sv[r] = bmx; si[r] = cidx[bpp];
        }
        float mx = sv[0];
        float ee[8]; float den = 0.f;
#pragma unroll
        for (int r = 0; r < 8; ++r) { ee[r] = expf(sv[r] - mx); den += ee[r]; }
#pragma unroll
        for (int r = 0; r < 8; ++r) { attn_s[r] = ee[r] / den; vidx_s[r] = si[r]; }
    }
    __syncthreads();
    int d0 = t * 2;
    float c0 = 0.f, c1 = 0.f;
#pragma unroll
    for (int r = 0; r < 8; ++r) {
        float w = attn_s[r];
        const float* vrow = values + (size_t)vidx_s[r] * 512;
        float2 vv = *(const float2*)(vrow + d0);
        c0 += w * vv.x; c1 += w * vv.y;
    }
    float2 outv; outv.x = c0; outv.y = c1;
    *(float2*)(context + (size_t)b * 512 + d0) = outv;
}

// ---------------------------------------------------------------------------
// logits v2: same pipelined structure as sims v2. 32 K-steps of 32.
// ---------------------------------------------------------------------------
__global__ __launch_bounds__(256, 2) void logits_kernel(
    const float* __restrict__ Wp2, const float* __restrict__ bp2,
    const unsigned short* __restrict__ gh, float* __restrict__ out)
{
    __shared__ unsigned short Ah[2][256 * 32];   // 2 x 16 KB
    __shared__ unsigned short Bw[2][128 * 32];   // 2 x 8 KB
    __shared__ float bias_s[128];
    int t = threadIdx.x, lane = t & 63, wid = t >> 6;
    int fr = lane & 15, fq = lane >> 4;
    int vbase = blockIdx.x * 128;
    int b0 = (wid >> 1) * 128;
    int m0 = (wid & 1) * 64;
    if (t < 128) { int gv = vbase + t; bias_s[t] = (gv < VDIM) ? bp2[gv] : 0.f; }

    f4_t acc[8][4];
#pragma unroll
    for (int i = 0; i < 8; ++i)
#pragma unroll
        for (int j = 0; j < 4; ++j) acc[i][j] = (f4_t){0.f, 0.f, 0.f, 0.f};

    const int bml0 = t >> 3, bkq = t & 7;
    int   gvr[4];  bool gvv[4];
#pragma unroll
    for (int jj = 0; jj < 4; ++jj) {
        gvr[jj] = vbase + bml0 + 32 * jj;
        gvv[jj] = gvr[jj] < VDIM;
    }

    // ---- prologue: stage step 0 into buffer 0 ----
#pragma unroll
    for (int j = 0; j < 4; ++j) {
        int c = t + 256 * j;
        int row = c >> 2, slot = c & 3;
        int ach = slot ^ ((row >> 1) & 3);
        glds16(gh + (size_t)row * 1024 + ach * 8, &Ah[0][c * 8]);
    }
    float4 kreg[4];
#pragma unroll
    for (int jj = 0; jj < 4; ++jj)
        kreg[jj] = gvv[jj] ? *(const float4*)(Wp2 + (size_t)gvr[jj] * 1024 + bkq * 4)
                           : (float4){0.f, 0.f, 0.f, 0.f};
#pragma unroll
    for (int jj = 0; jj < 4; ++jj) {
        int ml = bml0 + 32 * jj;
        float4 v = kreg[jj];
        us4_t pk; pk[0] = f2bf(v.x); pk[1] = f2bf(v.y); pk[2] = f2bf(v.z); pk[3] = f2bf(v.w);
        int slot = (bkq >> 1) ^ ((ml >> 1) & 3);
        *(us4_t*)(void*)(&Bw[0][ml * 32 + slot * 8 + (bkq & 1) * 4]) = pk;
    }
    __syncthreads();

    for (int s = 0; s < 32; ++s) {
        int cur = s & 1, nxt = cur ^ 1;
        if (s < 31) {
#pragma unroll
            for (int jj = 0; jj < 4; ++jj)
                kreg[jj] = gvv[jj]
                    ? *(const float4*)(Wp2 + (size_t)gvr[jj] * 1024 + (s + 1) * 32 + bkq * 4)
                    : (float4){0.f, 0.f, 0.f, 0.f};
#pragma unroll
            for (int j = 0; j < 4; ++j) {
                int c = t + 256 * j;
                int row = c >> 2, slot = c & 3;
                int ach = slot ^ ((row >> 1) & 3);
                glds16(gh + (size_t)row * 1024 + (s + 1) * 32 + ach * 8, &Ah[nxt][c * 8]);
            }
        }
        bf8_t af[8], bfr[4];
        int slotr = fq ^ ((fr >> 1) & 3);
#pragma unroll
        for (int i = 0; i < 8; ++i)
            af[i] = *(const bf8_t*)(const void*)(&Ah[cur][(b0 + i * 16 + fr) * 32 + slotr * 8]);
#pragma unroll
        for (int j = 0; j < 4; ++j)
            bfr[j] = *(const bf8_t*)(const void*)(&Bw[cur][(m0 + j * 16 + fr) * 32 + slotr * 8]);
#pragma unroll
        for (int i = 0; i < 8; ++i)
#pragma unroll
            for (int j = 0; j < 4; ++j)
                acc[i][j] = __builtin_amdgcn_mfma_f32_16x16x32_bf16(af[i], bfr[j], acc[i][j], 0, 0, 0);
        if (s < 31) {
#pragma unroll
            for (int jj = 0; jj < 4; ++jj) {
                int ml = bml0 + 32 * jj;
                float4 v = kreg[jj];
                us4_t pk; pk[0] = f2bf(v.x); pk[1] = f2bf(v.y); pk[2] = f2bf(v.z); pk[3] = f2bf(v.w);
                int slot = (bkq >> 1) ^ ((ml >> 1) & 3);
                *(us4_t*)(void*)(&Bw[nxt][ml * 32 + slot * 8 + (bkq & 1) * 4]) = pk;
            }
        }
        __syncthreads();
    }
#pragma unroll
    for (int i = 0; i < 8; ++i) {
        int brow = b0 + i * 16 + fq * 4;
#pragma unroll
        for (int j = 0; j < 4; ++j) {
            int vloc = m0 + j * 16 + fr;
            int gv = vbase + vloc;
            if (gv < VDIM) {
                float bias = bias_s[vloc];
#pragma unroll
                for (int r = 0; r < 4; ++r)
                    out[(size_t)(brow + r) * VDIM + gv] = acc[i][j][r] + bias;
            }
        }
    }
}

// ---------------------------------------------------------------------------
// value head: out[B*V + b] = h_v[b,:] . Wv2 + bv2.  One wave per batch row.
// ---------------------------------------------------------------------------
__global__ __launch_bounds__(256) void value_kernel(
    const float* __restrict__ hcomb, const float* __restrict__ Wv2,
    const float* __restrict__ bv2, float* __restrict__ out)
{
    int lane = threadIdx.x & 63, wid = threadIdx.x >> 6;
    int b = blockIdx.x * 4 + wid;
    float s = 0.f;
#pragma unroll
    for (int i = 0; i < 16; ++i) {
        int k = lane + 64 * i;
        s += hcomb[(size_t)b * 2048 + 1024 + k] * Wv2[k];
    }
#pragma unroll
    for (int off = 32; off; off >>= 1) s += __shfl_down(s, off);
    if (lane == 0) out[(size_t)BB * VDIM + b] = s + bv2[0];
}

// ---------------------------------------------------------------------------
extern "C" void kernel_launch(void* const* d_in, const int* in_sizes, int n_in,
                              void* d_out, int out_size, void* d_ws, size_t ws_size,
                              hipStream_t stream)
{
    const float* hidden = (const float*)d_in[0];
    const float* keys   = (const float*)d_in[1];
    const float* values = (const float*)d_in[2];
    const float* imp    = (const float*)d_in[3];
    const float* Wq  = (const float*)d_in[4];
    const float* bq  = (const float*)d_in[5];
    const float* Wp1 = (const float*)d_in[6];
    const float* bp1 = (const float*)d_in[7];
    const float* Wp2 = (const float*)d_in[8];
    const float* bp2 = (const float*)d_in[9];
    const float* Wv1 = (const float*)d_in[10];
    const float* bv1 = (const float*)d_in[11];
    const float* Wv2 = (const float*)d_in[12];
    const float* bv2 = (const float*)d_in[13];
    // d_in[14] = top_k (always 8 in this problem's setup)
    float* out = (float*)d_out;
    char* ws = (char*)d_ws;

    float*          query   = (float*)(ws + 0);                      // 524288 B
    float*          qinv    = (float*)(ws + 524288);                 //   1024 B
    unsigned short* gq      = (unsigned short*)(ws + 525312);        // 262144 B
    float*          context = (float*)(ws + 787456);                 // 524288 B
    float*          hcomb   = (float*)(ws + 1311744);                // 2097152 B
    unsigned short* gh      = (unsigned short*)(ws + 3408896);       // 524288 B
    unsigned short* scores  = (unsigned short*)(ws + 3933184);       // 51200000 B
    // candidate buffers OVERLAY the hcomb region (consumed before step 5).
    float* cand_val = (float*)(ws + 1311744);                        // 409600 B
    int*   cand_idx = (int*)  (ws + 1311744 + 409600);               // 409600 B

    // 1. query = hidden @ Wq^T + bq   (exact f32 — selection depends on it)
    gemm_f32_kernel<16, 64><<<dim3(16, 8), 256, 0, stream>>>(
        hidden, 1024, nullptr, 0, Wq, bq, nullptr, nullptr, 512, 512, 0, query, nullptr);
    // 2. query norms + bf16 copy
    qprep_kernel<<<256, 256, 0, stream>>>(query, qinv, gq);
    // 3. approx sims (pipelined bf16 MFMA) -> bf16 score matrix
    sims_kernel<<<782, 256, 0, stream>>>(keys, imp, gq, qinv, scores);
    // 4a. chunked exact top-16 per (row, chunk)
    topk_stage1_kernel<<<dim3(TK_NCH, 256), 256, 0, stream>>>(scores, cand_val, cand_idx);
    // 4b. merge 400 candidates -> top-16 -> exact rescore -> top-8 -> context
    topk_refine2_kernel<<<256, 256, 0, stream>>>(
        cand_val, cand_idx, keys, values, imp, query, qinv, context);
    // 5. h_p / h_v = relu([hidden|context] @ [Wp1;Wv1]^T + b)  (f32, emits bf16 h_p)
    gemm_f32_kernel<32, 64><<<dim3(8, 32), 256, 0, stream>>>(
        hidden, 1024, context, 512, Wp1, bp1, Wv1, bv1, 1024, 2048, 1, hcomb, gh);
    // 6. logits = h_p @ Wp2^T + bp2  (pipelined bf16 MFMA, f32 out)
    logits_kernel<<<393, 256, 0, stream>>>(Wp2, bp2, gh, out);
    // 7. value head
    value_kernel<<<64, 256, 0, stream>>>(hcomb, Wv2, bv2, out);
}